// Round 9
// baseline (263.337 us; speedup 1.0000x reference)
//
#include <hip/hip_runtime.h>
#include <cstdint>
#include <cstddef>

#define NC 64
#define LN2 0.6931471805599453f

typedef _Float16 half2_t __attribute__((ext_vector_type(2)));
typedef unsigned int uint32x4 __attribute__((ext_vector_type(4)));

static __device__ __forceinline__ float dot2acc(uint32_t a, uint32_t b, float c) {
#if __has_builtin(__builtin_amdgcn_fdot2)
    return __builtin_amdgcn_fdot2(__builtin_bit_cast(half2_t, a),
                                  __builtin_bit_cast(half2_t, b), c, false);
#else
    half2_t ha = __builtin_bit_cast(half2_t, a), hb = __builtin_bit_cast(half2_t, b);
    return c + (float)ha[0] * (float)hb[0] + (float)ha[1] * (float)hb[1];
#endif
}

template <int CTRL>
static __device__ __forceinline__ uint32_t dpp_mov(uint32_t x) {
    return (uint32_t)__builtin_amdgcn_update_dpp(0, (int)x, CTRL, 0xf, 0xf, true);
}
template <int CTRL>
static __device__ __forceinline__ float dppf(float x) {
    return __int_as_float(__builtin_amdgcn_update_dpp(
        0, __float_as_int(x), CTRL, 0xf, 0xf, true));
}
static __device__ __forceinline__ float wave_sum_bcast(float x) {
    x = x + dppf<0x111>(x);
    x = x + dppf<0x112>(x);
    x = x + dppf<0x114>(x);
    x = x + dppf<0x118>(x);
    x = x + dppf<0x142>(x);   // row_bcast15
    x = x + dppf<0x143>(x);   // row_bcast31
    return __int_as_float(__builtin_amdgcn_readlane(__float_as_int(x), 63));
}

// DPP ctrls: 0xB1 quad[1,0,3,2]=^1, 0x4E quad[2,3,0,1]=^2, 0x1B quad[3,2,1,0]=^3,
//            0x140 row_mirror=^15, 0x141 row_half_mirror=^7

__global__ __launch_bounds__(64, 1)
void crf_nll_kernel(const float* __restrict__ logits,
                    const float* __restrict__ trans,
                    const float* __restrict__ init_alphas,
                    const int*  __restrict__ lengths,
                    const int*  __restrict__ tags,
                    float* __restrict__ out,
                    int N, int T)
{
    const int n = blockIdx.x;
    const int lane = threadIdx.x;              // 0..63, owns class row `lane`
    const float* lg = logits + (size_t)n * T * NC;
    const int len = lengths[n];                // in [2, T]
    const int Tm1 = T - 1;

    __shared__ __align__(16) uint32_t E_st[64 * 32];   // exp(trans), f16x2, PERMUTED per row

    // ---- fill E_st with the butterfly-matched permutation.
    // Gathered state at position p comes from lane^D(p),
    // D(p) = 32*b0 ^ 16*b1 ^ 8*b2 ^ 4*b3 ^ 2*b4 (levels: bp32, swz16, dpp8, dpp4, dpp2).
    // So E_st[row][p] = pair q = (row>>1) ^ (D(p)>>1), with f16 halves swapped for odd rows.
    const float2* tr2 = reinterpret_cast<const float2*>(trans);
    #pragma unroll
    for (int i = lane; i < 64 * 32; i += 64) {
        int row = i >> 5, p = i & 31;
        int Dh = ((p & 1) << 4) | ((p & 2) << 2) | (p & 4) | ((p & 8) >> 2) | ((p & 16) >> 4);
        int q = ((row >> 1) ^ Dh) & 31;
        int par = row & 1;
        float2 t2 = tr2[row * 32 + q];         // classes 2q (x), 2q+1 (y)
        float vlo = par ? t2.y : t2.x;
        float vhi = par ? t2.x : t2.y;
        uint32_t lo = (uint32_t)__builtin_bit_cast(uint16_t, (_Float16)__expf(vlo));
        uint32_t hi = (uint32_t)__builtin_bit_cast(uint16_t, (_Float16)__expf(vhi));
        E_st[row * 32 + p] = lo | (hi << 16);
    }

    // ---- hoist this lane's permuted E row (128 B) into 8 vec4 regs via inline asm
    // (asm outputs are non-rematerializable -> stay resident; proven in round 8).
    uint32x4 e0, e1, e2, e3, e4, e5, e6, e7;
    {
        uint32_t e_addr = (uint32_t)(uintptr_t)&E_st[0] + (uint32_t)(lane * 128);
        asm volatile(
            "ds_read_b128 %0, %8 offset:0\n\t"
            "ds_read_b128 %1, %8 offset:16\n\t"
            "ds_read_b128 %2, %8 offset:32\n\t"
            "ds_read_b128 %3, %8 offset:48\n\t"
            "ds_read_b128 %4, %8 offset:64\n\t"
            "ds_read_b128 %5, %8 offset:80\n\t"
            "ds_read_b128 %6, %8 offset:96\n\t"
            "ds_read_b128 %7, %8 offset:112\n\t"
            "s_waitcnt lgkmcnt(0)"
            : "=&v"(e0), "=&v"(e1), "=&v"(e2), "=&v"(e3),
              "=&v"(e4), "=&v"(e5), "=&v"(e6), "=&v"(e7)
            : "v"(e_addr)
            : "memory");
        __builtin_amdgcn_sched_barrier(0);
    }

    // ---- init: alpha0 = init + logits[0]; lane-0 anchored at e^-8
    float a0 = init_alphas[lane] + lg[lane];
    float L  = __int_as_float(__builtin_amdgcn_readfirstlane(__float_as_int(a0)))
               + 8.f * LN2;
    float vcur = __expf(a0 - L);

    const int bp_addr = (lane ^ 32) << 2;      // ds_bpermute index for lane^32

    // Lagged power-of-2 normalization (exact): scale from step t applied at t+1.
    float s_cur = 1.0f;
    float dL    = 0.0f;

    auto step = [&](float raw) {
        float fs = __expf(raw) * s_cur;        // raw prefetched 8 steps ago: off-chain
        L += dL;

        // ---- butterfly all-gather: replicate the 64-f16 state into w[0..31]
        uint32_t w[32];
        uint32_t h  = (uint32_t)__builtin_bit_cast(uint16_t, (_Float16)vcur);
        uint32_t hp = dpp_mov<0xB1>(h);                    // lane^1
        w[0] = h | (hp << 16);                             // pair (own order by parity)
        w[1] = (uint32_t)__builtin_amdgcn_ds_bpermute(bp_addr, (int)w[0]);   // ^32
        w[2] = (uint32_t)__builtin_amdgcn_ds_swizzle((int)w[0], 0x401F);     // ^16
        w[3] = (uint32_t)__builtin_amdgcn_ds_swizzle((int)w[1], 0x401F);
        uint32_t t0 = dpp_mov<0x141>(w[0]);                // ^7 (shared by ^8 and ^4)
        uint32_t t1 = dpp_mov<0x141>(w[1]);
        uint32_t t2 = dpp_mov<0x141>(w[2]);
        uint32_t t3 = dpp_mov<0x141>(w[3]);
        w[4] = dpp_mov<0x140>(t0);                         // ^15 ∘ ^7 = ^8
        w[5] = dpp_mov<0x140>(t1);
        w[6] = dpp_mov<0x140>(t2);
        w[7] = dpp_mov<0x140>(t3);
        w[8]  = dpp_mov<0x1B>(t0);                         // ^3 ∘ ^7 = ^4
        w[9]  = dpp_mov<0x1B>(t1);
        w[10] = dpp_mov<0x1B>(t2);
        w[11] = dpp_mov<0x1B>(t3);
        uint32_t t4 = dpp_mov<0x141>(w[4]);
        uint32_t t5 = dpp_mov<0x141>(w[5]);
        uint32_t t6 = dpp_mov<0x141>(w[6]);
        uint32_t t7 = dpp_mov<0x141>(w[7]);
        w[12] = dpp_mov<0x1B>(t4);
        w[13] = dpp_mov<0x1B>(t5);
        w[14] = dpp_mov<0x1B>(t6);
        w[15] = dpp_mov<0x1B>(t7);
        #pragma unroll
        for (int i = 0; i < 16; ++i)                       // ^2
            w[16 + i] = dpp_mov<0x4E>(w[i]);

        // ---- dot with resident (permuted) E: 32 x v_dot2_f32_f16
        float c0 = 0.f, c1 = 0.f, c2 = 0.f, c3 = 0.f;
        float c4 = 0.f, c5 = 0.f, c6 = 0.f, c7 = 0.f;
        c0 = dot2acc(e0.x, w[0],  c0); c1 = dot2acc(e0.y, w[1],  c1);
        c2 = dot2acc(e0.z, w[2],  c2); c3 = dot2acc(e0.w, w[3],  c3);
        c4 = dot2acc(e1.x, w[4],  c4); c5 = dot2acc(e1.y, w[5],  c5);
        c6 = dot2acc(e1.z, w[6],  c6); c7 = dot2acc(e1.w, w[7],  c7);
        c0 = dot2acc(e2.x, w[8],  c0); c1 = dot2acc(e2.y, w[9],  c1);
        c2 = dot2acc(e2.z, w[10], c2); c3 = dot2acc(e2.w, w[11], c3);
        c4 = dot2acc(e3.x, w[12], c4); c5 = dot2acc(e3.y, w[13], c5);
        c6 = dot2acc(e3.z, w[14], c6); c7 = dot2acc(e3.w, w[15], c7);
        c0 = dot2acc(e4.x, w[16], c0); c1 = dot2acc(e4.y, w[17], c1);
        c2 = dot2acc(e4.z, w[18], c2); c3 = dot2acc(e4.w, w[19], c3);
        c4 = dot2acc(e5.x, w[20], c4); c5 = dot2acc(e5.y, w[21], c5);
        c6 = dot2acc(e5.z, w[22], c6); c7 = dot2acc(e5.w, w[23], c7);
        c0 = dot2acc(e6.x, w[24], c0); c1 = dot2acc(e6.y, w[25], c1);
        c2 = dot2acc(e6.z, w[26], c2); c3 = dot2acc(e6.w, w[27], c3);
        c4 = dot2acc(e7.x, w[28], c4); c5 = dot2acc(e7.y, w[29], c5);
        c6 = dot2acc(e7.z, w[30], c6); c7 = dot2acc(e7.w, w[31], c7);

        const float dot = ((c0 + c4) + (c1 + c5)) + ((c2 + c6) + (c3 + c7));
        float v = fs * dot;                    // new state (positive)
        vcur = v;

        // off-chain: next step's exact power-of-2 scale from lane-0 exponent
        unsigned bits = (unsigned)__builtin_amdgcn_readfirstlane((int)__float_as_uint(v));
        int e = (int)((bits >> 23) & 0xFF);
        s_cur = __uint_as_float((unsigned)(246 - e) << 23);       // 2^(119-e)
        dL    = (float)(e - 119) * LN2;
    };

    // ---- depth-8 prefetch in NAMED registers (counted vmcnt waits)
    float r0 = lg[NC * (1 < Tm1 ? 1 : Tm1) + lane];
    float r1 = lg[NC * (2 < Tm1 ? 2 : Tm1) + lane];
    float r2 = lg[NC * (3 < Tm1 ? 3 : Tm1) + lane];
    float r3 = lg[NC * (4 < Tm1 ? 4 : Tm1) + lane];
    float r4 = lg[NC * (5 < Tm1 ? 5 : Tm1) + lane];
    float r5 = lg[NC * (6 < Tm1 ? 6 : Tm1) + lane];
    float r6 = lg[NC * (7 < Tm1 ? 7 : Tm1) + lane];
    float r7 = lg[NC * (8 < Tm1 ? 8 : Tm1) + lane];

    int t = 1;
    for (; t + 8 <= len; t += 8) {
        int p;
        step(r0); p = t +  8; p = p < Tm1 ? p : Tm1; r0 = lg[NC * p + lane];
        step(r1); p = t +  9; p = p < Tm1 ? p : Tm1; r1 = lg[NC * p + lane];
        step(r2); p = t + 10; p = p < Tm1 ? p : Tm1; r2 = lg[NC * p + lane];
        step(r3); p = t + 11; p = p < Tm1 ? p : Tm1; r3 = lg[NC * p + lane];
        step(r4); p = t + 12; p = p < Tm1 ? p : Tm1; r4 = lg[NC * p + lane];
        step(r5); p = t + 13; p = p < Tm1 ? p : Tm1; r5 = lg[NC * p + lane];
        step(r6); p = t + 14; p = p < Tm1 ? p : Tm1; r6 = lg[NC * p + lane];
        step(r7); p = t + 15; p = p < Tm1 ? p : Tm1; r7 = lg[NC * p + lane];
    }
    if (t + 0 < len) step(r0);
    if (t + 1 < len) step(r1);
    if (t + 2 < len) step(r2);
    if (t + 3 < len) step(r3);
    if (t + 4 < len) step(r4);
    if (t + 5 < len) step(r5);
    if (t + 6 < len) step(r6);

    // ---- logZ = L + log(sum_i v_i)   (final unapplied s_cur/dL correctly excluded)
    const float logZ = L + __logf(wave_sum_bcast(vcur));

    // ---- gold score (parallel, off critical path)
    const int* tg = tags + (size_t)n * T;
    float g = 0.f;
    for (int tt = 1 + lane; tt < len; tt += 64) {
        const int cur = tg[tt];
        const int prv = tg[tt - 1];
        g += trans[cur * NC + prv] + lg[tt * NC + cur];
    }
    g = wave_sum_bcast(g);

    if (lane == 0) {
        const int t0 = tg[0];
        const float gold = init_alphas[t0] + lg[t0] + g;
        out[n] = logZ - gold;
    }
}

extern "C" void kernel_launch(void* const* d_in, const int* in_sizes, int n_in,
                              void* d_out, int out_size, void* d_ws, size_t ws_size,
                              hipStream_t stream)
{
    const float* logits = (const float*)d_in[0];   // [N][T][C] f32
    const float* trans  = (const float*)d_in[1];   // [C][C]    f32
    const float* inita  = (const float*)d_in[2];   // [C]       f32
    const int*   lens   = (const int*)d_in[3];     // [N]       i32
    const int*   tags   = (const int*)d_in[4];     // [N][T]    i32
    float*       out    = (float*)d_out;           // [N]       f32

    const int N = 512, T = 1024;
    crf_nll_kernel<<<N, 64, 0, stream>>>(logits, trans, inita, lens, tags, out, N, T);
}

// Round 10
// 252.663 us; speedup vs baseline: 1.0422x; 1.0422x over previous
//
#include <hip/hip_runtime.h>
#include <cstdint>
#include <cstddef>

#define NC 64
#define LN2 0.6931471805599453f

typedef _Float16 half2_t __attribute__((ext_vector_type(2)));
typedef unsigned int uint32x4 __attribute__((ext_vector_type(4)));

static __device__ __forceinline__ float dot2acc(uint32_t a, uint32_t b, float c) {
#if __has_builtin(__builtin_amdgcn_fdot2)
    return __builtin_amdgcn_fdot2(__builtin_bit_cast(half2_t, a),
                                  __builtin_bit_cast(half2_t, b), c, false);
#else
    half2_t ha = __builtin_bit_cast(half2_t, a), hb = __builtin_bit_cast(half2_t, b);
    return c + (float)ha[0] * (float)hb[0] + (float)ha[1] * (float)hb[1];
#endif
}

template <int CTRL>
static __device__ __forceinline__ uint32_t dpp_mov(uint32_t x) {
    return (uint32_t)__builtin_amdgcn_update_dpp(0, (int)x, CTRL, 0xf, 0xf, true);
}
template <int CTRL>
static __device__ __forceinline__ float dppf(float x) {
    return __int_as_float(__builtin_amdgcn_update_dpp(
        0, __float_as_int(x), CTRL, 0xf, 0xf, true));
}
static __device__ __forceinline__ float wave_sum_bcast(float x) {
    x = x + dppf<0x111>(x);
    x = x + dppf<0x112>(x);
    x = x + dppf<0x114>(x);
    x = x + dppf<0x118>(x);
    x = x + dppf<0x142>(x);   // row_bcast15
    x = x + dppf<0x143>(x);   // row_bcast31
    return __int_as_float(__builtin_amdgcn_readlane(__float_as_int(x), 63));
}

// VALU cross-lane swap pair: out0[i] = src[i & ~32], out1[i] = src[i | 32]
static __device__ __forceinline__ void pl32_pair(uint32_t src, uint32_t& o0, uint32_t& o1) {
    uint32_t a, b;
    asm("v_mov_b32 %0, %2\n\t"
        "v_mov_b32 %1, %2\n\t"
        "v_permlane32_swap_b32 %0, %1"
        : "=&v"(a), "=&v"(b) : "v"(src));
    o0 = a; o1 = b;
}
// out0[i] = src[i & ~16], out1[i] = src[i | 16]
static __device__ __forceinline__ void pl16_pair(uint32_t src, uint32_t& o0, uint32_t& o1) {
    uint32_t a, b;
    asm("v_mov_b32 %0, %2\n\t"
        "v_mov_b32 %1, %2\n\t"
        "v_permlane16_swap_b32 %0, %1"
        : "=&v"(a), "=&v"(b) : "v"(src));
    o0 = a; o1 = b;
}

// DPP ctrls: 0xB1 ^1, 0x4E ^2, 0x1B ^3, 0x141 ^7 (half_mirror), 0x140 ^15 (mirror)

__global__ __launch_bounds__(64, 1)
void crf_nll_kernel(const float* __restrict__ logits,
                    const float* __restrict__ trans,
                    const float* __restrict__ init_alphas,
                    const int*  __restrict__ lengths,
                    const int*  __restrict__ tags,
                    float* __restrict__ out,
                    int N, int T)
{
    const int n = blockIdx.x;
    const int lane = threadIdx.x;              // 0..63, owns class row `lane`
    const float* lg = logits + (size_t)n * T * NC;
    const int len = lengths[n];                // in [2, T]
    const int Tm1 = T - 1;

    __shared__ __align__(16) uint32_t E_st[64 * 32];   // exp(trans) f16x2, permuted per row

    // ---- fill E_st matched to the all-VALU butterfly below.
    // Word p (per lane i) will hold state classes {g, g^1} where
    //   p = 8k + 2m + n,  g = ((i & 15) ^ (4m + 2n)) | (k << 4)
    // (k = bits5..4 value from permlane swaps; 4m+2n = XOR distance from DPP mirrors;
    //  bit0 comes from the ^1 pairing, so g inherits i's bit0.)
    const float* tr = trans;
    #pragma unroll
    for (int i = lane; i < 64 * 32; i += 64) {
        int row = i >> 5, p = i & 31;
        int k = p >> 3, m = (p >> 1) & 3, nn = p & 1;
        int g = ((row & 15) ^ (4 * m + 2 * nn)) | (k << 4);
        uint32_t lo = (uint32_t)__builtin_bit_cast(uint16_t, (_Float16)__expf(tr[row * NC + g]));
        uint32_t hi = (uint32_t)__builtin_bit_cast(uint16_t, (_Float16)__expf(tr[row * NC + (g ^ 1)]));
        E_st[row * 32 + p] = lo | (hi << 16);
    }

    // ---- hoist this lane's permuted E row (128 B) into 8 vec4 regs via inline asm
    // (asm outputs are non-rematerializable -> stay resident; proven round 8).
    uint32x4 e0, e1, e2, e3, e4, e5, e6, e7;
    {
        uint32_t e_addr = (uint32_t)(uintptr_t)&E_st[0] + (uint32_t)(lane * 128);
        asm volatile(
            "ds_read_b128 %0, %8 offset:0\n\t"
            "ds_read_b128 %1, %8 offset:16\n\t"
            "ds_read_b128 %2, %8 offset:32\n\t"
            "ds_read_b128 %3, %8 offset:48\n\t"
            "ds_read_b128 %4, %8 offset:64\n\t"
            "ds_read_b128 %5, %8 offset:80\n\t"
            "ds_read_b128 %6, %8 offset:96\n\t"
            "ds_read_b128 %7, %8 offset:112\n\t"
            "s_waitcnt lgkmcnt(0)"
            : "=&v"(e0), "=&v"(e1), "=&v"(e2), "=&v"(e3),
              "=&v"(e4), "=&v"(e5), "=&v"(e6), "=&v"(e7)
            : "v"(e_addr)
            : "memory");
        __builtin_amdgcn_sched_barrier(0);
    }

    // ---- init: alpha0 = init + logits[0]; lane-0 anchored at e^-8
    float a0 = init_alphas[lane] + lg[lane];
    float L  = __int_as_float(__builtin_amdgcn_readfirstlane(__float_as_int(a0)))
               + 8.f * LN2;
    float vcur = __expf(a0 - L);

    // Lagged power-of-2 normalization (exact): scale from step t applied at t+1.
    float s_cur = 1.0f;
    float dL    = 0.0f;

    auto step = [&](float raw) {
        float fs = __expf(raw) * s_cur;        // raw prefetched 8 steps ago: off-chain
        L += dL;

        // ---- all-VALU butterfly all-gather of the 64-f16 state into 32 words
        uint32_t c  = (uint32_t)__builtin_bit_cast(uint16_t, (_Float16)vcur);
        uint32_t h  = c | (dpp_mov<0xB1>(c) << 16);        // pair {v[i], v[i^1]}

        uint32_t a0w, a1w;                                  // bit5: {&~32, |32}
        pl32_pair(h, a0w, a1w);
        uint32_t b0, b1, b2, b3;                            // bit4: 4 (k) bases
        pl16_pair(a0w, b0, b1);                             // k=0,1
        pl16_pair(a1w, b2, b3);                             // k=2,3

        // per base u: words {u, u^2, u^4, u^6, u^8, u^10, u^12, u^14} (order p=8k+2m+n)
        float s0 = 0.f, s1 = 0.f, s2 = 0.f, s3 = 0.f;
        float s4 = 0.f, s5 = 0.f, s6 = 0.f, s7 = 0.f;
#define BASE_DOTS(u, ea, eb, A, B, C, D)                                   \
        {                                                                  \
            uint32_t t_ = dpp_mov<0x141>(u);   /* u^7  */                  \
            uint32_t q_ = dpp_mov<0x1B>(u);    /* u^3  */                  \
            uint32_t m4_  = dpp_mov<0x1B>(t_);  /* u^4  */                 \
            uint32_t m8_  = dpp_mov<0x140>(t_); /* u^8  */                 \
            uint32_t m12_ = dpp_mov<0x140>(q_); /* u^12 */                 \
            A = dot2acc(ea.x, u,                 A);                       \
            B = dot2acc(ea.y, dpp_mov<0x4E>(u),   B);                      \
            C = dot2acc(ea.z, m4_,               C);                       \
            D = dot2acc(ea.w, dpp_mov<0x4E>(m4_), D);                      \
            A = dot2acc(eb.x, m8_,               A);                       \
            B = dot2acc(eb.y, dpp_mov<0x4E>(m8_), B);                      \
            C = dot2acc(eb.z, m12_,              C);                       \
            D = dot2acc(eb.w, dpp_mov<0x4E>(m12_),D);                      \
        }
        BASE_DOTS(b0, e0, e1, s0, s1, s2, s3)
        BASE_DOTS(b1, e2, e3, s4, s5, s6, s7)
        BASE_DOTS(b2, e4, e5, s0, s1, s2, s3)
        BASE_DOTS(b3, e6, e7, s4, s5, s6, s7)
#undef BASE_DOTS

        const float dot = ((s0 + s4) + (s1 + s5)) + ((s2 + s6) + (s3 + s7));
        float v = fs * dot;                    // new state (positive)
        vcur = v;

        // off-chain: next step's exact power-of-2 scale from lane-0 exponent
        unsigned bits = (unsigned)__builtin_amdgcn_readfirstlane((int)__float_as_uint(v));
        int e = (int)((bits >> 23) & 0xFF);
        s_cur = __uint_as_float((unsigned)(246 - e) << 23);       // 2^(119-e)
        dL    = (float)(e - 119) * LN2;
    };

    // ---- depth-8 prefetch in NAMED registers (counted vmcnt waits)
    float r0 = lg[NC * (1 < Tm1 ? 1 : Tm1) + lane];
    float r1 = lg[NC * (2 < Tm1 ? 2 : Tm1) + lane];
    float r2 = lg[NC * (3 < Tm1 ? 3 : Tm1) + lane];
    float r3 = lg[NC * (4 < Tm1 ? 4 : Tm1) + lane];
    float r4 = lg[NC * (5 < Tm1 ? 5 : Tm1) + lane];
    float r5 = lg[NC * (6 < Tm1 ? 6 : Tm1) + lane];
    float r6 = lg[NC * (7 < Tm1 ? 7 : Tm1) + lane];
    float r7 = lg[NC * (8 < Tm1 ? 8 : Tm1) + lane];

    int t = 1;
    for (; t + 8 <= len; t += 8) {
        int p;
        step(r0); p = t +  8; p = p < Tm1 ? p : Tm1; r0 = lg[NC * p + lane];
        step(r1); p = t +  9; p = p < Tm1 ? p : Tm1; r1 = lg[NC * p + lane];
        step(r2); p = t + 10; p = p < Tm1 ? p : Tm1; r2 = lg[NC * p + lane];
        step(r3); p = t + 11; p = p < Tm1 ? p : Tm1; r3 = lg[NC * p + lane];
        step(r4); p = t + 12; p = p < Tm1 ? p : Tm1; r4 = lg[NC * p + lane];
        step(r5); p = t + 13; p = p < Tm1 ? p : Tm1; r5 = lg[NC * p + lane];
        step(r6); p = t + 14; p = p < Tm1 ? p : Tm1; r6 = lg[NC * p + lane];
        step(r7); p = t + 15; p = p < Tm1 ? p : Tm1; r7 = lg[NC * p + lane];
    }
    if (t + 0 < len) step(r0);
    if (t + 1 < len) step(r1);
    if (t + 2 < len) step(r2);
    if (t + 3 < len) step(r3);
    if (t + 4 < len) step(r4);
    if (t + 5 < len) step(r5);
    if (t + 6 < len) step(r6);

    // ---- logZ = L + log(sum_i v_i)   (final unapplied s_cur/dL correctly excluded)
    const float logZ = L + __logf(wave_sum_bcast(vcur));

    // ---- gold score (parallel, off critical path)
    const int* tg = tags + (size_t)n * T;
    float g = 0.f;
    for (int tt = 1 + lane; tt < len; tt += 64) {
        const int cur = tg[tt];
        const int prv = tg[tt - 1];
        g += trans[cur * NC + prv] + lg[tt * NC + cur];
    }
    g = wave_sum_bcast(g);

    if (lane == 0) {
        const int t0 = tg[0];
        const float gold = init_alphas[t0] + lg[t0] + g;
        out[n] = logZ - gold;
    }
}

extern "C" void kernel_launch(void* const* d_in, const int* in_sizes, int n_in,
                              void* d_out, int out_size, void* d_ws, size_t ws_size,
                              hipStream_t stream)
{
    const float* logits = (const float*)d_in[0];   // [N][T][C] f32
    const float* trans  = (const float*)d_in[1];   // [C][C]    f32
    const float* inita  = (const float*)d_in[2];   // [C]       f32
    const int*   lens   = (const int*)d_in[3];     // [N]       i32
    const int*   tags   = (const int*)d_in[4];     // [N][T]    i32
    float*       out    = (float*)d_out;           // [N]       f32

    const int N = 512, T = 1024;
    crf_nll_kernel<<<N, 64, 0, stream>>>(logits, trans, inita, lens, tags, out, N, T);
}

// Round 11
// 136.433 us; speedup vs baseline: 1.9302x; 1.8519x over previous
//
#include <hip/hip_runtime.h>
#include <cstdint>
#include <cstddef>

#define NC 64
#define LN2 0.6931471805599453f

typedef _Float16 half2_t __attribute__((ext_vector_type(2)));
typedef unsigned int uint32x4 __attribute__((ext_vector_type(4)));

static __device__ __forceinline__ float dot2acc(uint32_t a, uint32_t b, float c) {
#if __has_builtin(__builtin_amdgcn_fdot2)
    return __builtin_amdgcn_fdot2(__builtin_bit_cast(half2_t, a),
                                  __builtin_bit_cast(half2_t, b), c, false);
#else
    half2_t ha = __builtin_bit_cast(half2_t, a), hb = __builtin_bit_cast(half2_t, b);
    return c + (float)ha[0] * (float)hb[0] + (float)ha[1] * (float)hb[1];
#endif
}

template <int CTRL>
static __device__ __forceinline__ float dppf(float x) {
    return __int_as_float(__builtin_amdgcn_update_dpp(
        0, __float_as_int(x), CTRL, 0xf, 0xf, true));
}
static __device__ __forceinline__ float wave_sum_bcast(float x) {
    x = x + dppf<0x111>(x);
    x = x + dppf<0x112>(x);
    x = x + dppf<0x114>(x);
    x = x + dppf<0x118>(x);
    x = x + dppf<0x142>(x);   // row_bcast15
    x = x + dppf<0x143>(x);   // row_bcast31
    return __int_as_float(__builtin_amdgcn_readlane(__float_as_int(x), 63));
}

__global__ __launch_bounds__(128, 1)
void crf_nll_kernel(const float* __restrict__ logits,
                    const float* __restrict__ trans,
                    const float* __restrict__ init_alphas,
                    const int*  __restrict__ lengths,
                    const int*  __restrict__ tags,
                    float* __restrict__ out,
                    int N, int T)
{
    const int n = blockIdx.x;
    const int tid = threadIdx.x;
    const int wid = tid >> 6;          // wave 0: forward alpha; wave 1: backward beta
    const int lane = tid & 63;
    const float* lg = logits + (size_t)n * T * NC;
    const int len = lengths[n];        // in [2, T]
    const int Tm1 = T - 1;

    __shared__ __align__(16) uint32_t Etab[2][64 * 32]; // [0]=exp(E) rows, [1]=exp(E)^T rows, f16x2
    __shared__ __align__(16) uint16_t st_pk[2][NC + 8]; // per-wave state exchange (f16)
    __shared__ __align__(16) float xchg[2][NC];         // final f32 states
    __shared__ float Lsh[2], gsh[2];

    // ---- fill both tables (both waves cooperate)
    #pragma unroll
    for (int i = tid; i < 2 * 64 * 32; i += 128) {
        int tab = i >> 11, idx = i & 2047;
        int row = idx >> 5, k = idx & 31;
        float x0 = (tab == 0) ? trans[row * NC + 2 * k]     : trans[(2 * k) * NC + row];
        float x1 = (tab == 0) ? trans[row * NC + 2 * k + 1] : trans[(2 * k + 1) * NC + row];
        uint32_t lo = (uint32_t)__builtin_bit_cast(uint16_t, (_Float16)__expf(x0));
        uint32_t hi = (uint32_t)__builtin_bit_cast(uint16_t, (_Float16)__expf(x1));
        Etab[tab][idx] = lo | (hi << 16);
    }
    __syncthreads();

    // ---- hoist this wave's 128B matrix row into 8 vec4 regs via inline asm
    // (asm outputs non-rematerializable -> resident; proven round 8)
    uint32x4 e0, e1, e2, e3, e4, e5, e6, e7;
    {
        uint32_t e_addr = (uint32_t)(uintptr_t)&Etab[wid][0] + (uint32_t)(lane * 128);
        asm volatile(
            "ds_read_b128 %0, %8 offset:0\n\t"
            "ds_read_b128 %1, %8 offset:16\n\t"
            "ds_read_b128 %2, %8 offset:32\n\t"
            "ds_read_b128 %3, %8 offset:48\n\t"
            "ds_read_b128 %4, %8 offset:64\n\t"
            "ds_read_b128 %5, %8 offset:80\n\t"
            "ds_read_b128 %6, %8 offset:96\n\t"
            "ds_read_b128 %7, %8 offset:112\n\t"
            "s_waitcnt lgkmcnt(0)"
            : "=&v"(e0), "=&v"(e1), "=&v"(e2), "=&v"(e3),
              "=&v"(e4), "=&v"(e5), "=&v"(e6), "=&v"(e7)
            : "v"(e_addr)
            : "memory");
        __builtin_amdgcn_sched_barrier(0);
    }

    const int m  = (len - 1) >> 1;     // meeting point: forward does m steps
    const int nb = len - 1 - m;        // backward does nb >= 1 steps

    const uint32x4* vb4 = reinterpret_cast<const uint32x4*>(st_pk[wid]);
    uint16_t* my_pk = st_pk[wid];

    float L = 0.f, vcur = 1.0f, s_cur = 1.0f, dL = 0.0f;

    auto dotE = [&]() -> float {
        float c0 = 0.f, c1 = 0.f, c2 = 0.f, c3 = 0.f;
        float c4 = 0.f, c5 = 0.f, c6 = 0.f, c7 = 0.f;
        uint32x4 w;
        w = vb4[0];
        c0 = dot2acc(e0.x, w.x, c0); c1 = dot2acc(e0.y, w.y, c1);
        c2 = dot2acc(e0.z, w.z, c2); c3 = dot2acc(e0.w, w.w, c3);
        w = vb4[1];
        c4 = dot2acc(e1.x, w.x, c4); c5 = dot2acc(e1.y, w.y, c5);
        c6 = dot2acc(e1.z, w.z, c6); c7 = dot2acc(e1.w, w.w, c7);
        w = vb4[2];
        c0 = dot2acc(e2.x, w.x, c0); c1 = dot2acc(e2.y, w.y, c1);
        c2 = dot2acc(e2.z, w.z, c2); c3 = dot2acc(e2.w, w.w, c3);
        w = vb4[3];
        c4 = dot2acc(e3.x, w.x, c4); c5 = dot2acc(e3.y, w.y, c5);
        c6 = dot2acc(e3.z, w.z, c6); c7 = dot2acc(e3.w, w.w, c7);
        w = vb4[4];
        c0 = dot2acc(e4.x, w.x, c0); c1 = dot2acc(e4.y, w.y, c1);
        c2 = dot2acc(e4.z, w.z, c2); c3 = dot2acc(e4.w, w.w, c3);
        w = vb4[5];
        c4 = dot2acc(e5.x, w.x, c4); c5 = dot2acc(e5.y, w.y, c5);
        c6 = dot2acc(e5.z, w.z, c6); c7 = dot2acc(e5.w, w.w, c7);
        w = vb4[6];
        c0 = dot2acc(e6.x, w.x, c0); c1 = dot2acc(e6.y, w.y, c1);
        c2 = dot2acc(e6.z, w.z, c2); c3 = dot2acc(e6.w, w.w, c3);
        w = vb4[7];
        c4 = dot2acc(e7.x, w.x, c4); c5 = dot2acc(e7.y, w.y, c5);
        c6 = dot2acc(e7.z, w.z, c6); c7 = dot2acc(e7.w, w.w, c7);
        return ((c0 + c4) + (c1 + c5)) + ((c2 + c6) + (c3 + c7));
    };

    if (wid == 0) {
        // ---------------- forward: alpha_0 .. alpha_m ----------------
        float a0 = init_alphas[lane] + lg[lane];
        L = __int_as_float(__builtin_amdgcn_readfirstlane(__float_as_int(a0))) + 8.f * LN2;
        vcur = __expf(a0 - L);
        my_pk[lane] = __builtin_bit_cast(uint16_t, (_Float16)vcur);

        auto fstep = [&](float raw) {
            float fs = __expf(raw) * s_cur;
            L += dL;
            float v = fs * dotE();
            vcur = v;
            my_pk[lane] = __builtin_bit_cast(uint16_t, (_Float16)v);
            unsigned bits = (unsigned)__builtin_amdgcn_readfirstlane((int)__float_as_uint(v));
            int e = (int)((bits >> 23) & 0xFF);
            s_cur = __uint_as_float((unsigned)(246 - e) << 23);   // 2^(119-e)
            dL    = (float)(e - 119) * LN2;
        };

        float r0 = lg[NC * (1 < Tm1 ? 1 : Tm1) + lane];
        float r1 = lg[NC * (2 < Tm1 ? 2 : Tm1) + lane];
        float r2 = lg[NC * (3 < Tm1 ? 3 : Tm1) + lane];
        float r3 = lg[NC * (4 < Tm1 ? 4 : Tm1) + lane];
        float r4 = lg[NC * (5 < Tm1 ? 5 : Tm1) + lane];
        float r5 = lg[NC * (6 < Tm1 ? 6 : Tm1) + lane];
        float r6 = lg[NC * (7 < Tm1 ? 7 : Tm1) + lane];
        float r7 = lg[NC * (8 < Tm1 ? 8 : Tm1) + lane];

        int t = 1;
        for (; t + 8 <= m + 1; t += 8) {   // steps t .. t+7, all <= m
            int p;
            fstep(r0); p = t +  8; p = p < Tm1 ? p : Tm1; r0 = lg[NC * p + lane];
            fstep(r1); p = t +  9; p = p < Tm1 ? p : Tm1; r1 = lg[NC * p + lane];
            fstep(r2); p = t + 10; p = p < Tm1 ? p : Tm1; r2 = lg[NC * p + lane];
            fstep(r3); p = t + 11; p = p < Tm1 ? p : Tm1; r3 = lg[NC * p + lane];
            fstep(r4); p = t + 12; p = p < Tm1 ? p : Tm1; r4 = lg[NC * p + lane];
            fstep(r5); p = t + 13; p = p < Tm1 ? p : Tm1; r5 = lg[NC * p + lane];
            fstep(r6); p = t + 14; p = p < Tm1 ? p : Tm1; r6 = lg[NC * p + lane];
            fstep(r7); p = t + 15; p = p < Tm1 ? p : Tm1; r7 = lg[NC * p + lane];
        }
        if (t + 0 <= m) fstep(r0);
        if (t + 1 <= m) fstep(r1);
        if (t + 2 <= m) fstep(r2);
        if (t + 3 <= m) fstep(r3);
        if (t + 4 <= m) fstep(r4);
        if (t + 5 <= m) fstep(r5);
        if (t + 6 <= m) fstep(r6);
        // alpha_m = log(vcur) + L
    } else {
        // ---------------- backward: beta_{len-1}=0 down to beta_m ----------------
        // step k (k=0..nb-1): consumes logit row (len-1-k), produces beta_{len-2-k}
        auto bstep = [&](float raw) {
            float p = __expf(raw) * s_cur * vcur;   // f * (scaled u): own-lane product
            L += dL;
            my_pk[lane] = __builtin_bit_cast(uint16_t, (_Float16)p);
            float u = dotE();                        // E^T gather
            vcur = u;
            unsigned bits = (unsigned)__builtin_amdgcn_readfirstlane((int)__float_as_uint(u));
            int e = (int)((bits >> 23) & 0xFF);
            s_cur = __uint_as_float((unsigned)(246 - e) << 23);   // 2^(119-e)
            dL    = (float)(e - 119) * LN2;
        };

        int p0;
        p0 = len - 1;     p0 = p0 > 1 ? p0 : 1; float r0 = lg[NC * p0 + lane];
        p0 = len - 2;     p0 = p0 > 1 ? p0 : 1; float r1 = lg[NC * p0 + lane];
        p0 = len - 3;     p0 = p0 > 1 ? p0 : 1; float r2 = lg[NC * p0 + lane];
        p0 = len - 4;     p0 = p0 > 1 ? p0 : 1; float r3 = lg[NC * p0 + lane];
        p0 = len - 5;     p0 = p0 > 1 ? p0 : 1; float r4 = lg[NC * p0 + lane];
        p0 = len - 6;     p0 = p0 > 1 ? p0 : 1; float r5 = lg[NC * p0 + lane];
        p0 = len - 7;     p0 = p0 > 1 ? p0 : 1; float r6 = lg[NC * p0 + lane];
        p0 = len - 8;     p0 = p0 > 1 ? p0 : 1; float r7 = lg[NC * p0 + lane];

        int k = 0;
        for (; k + 8 <= nb; k += 8) {      // steps k .. k+7, all < nb
            int p;
            bstep(r0); p = len - 1 - (k +  8); p = p > 1 ? p : 1; r0 = lg[NC * p + lane];
            bstep(r1); p = len - 1 - (k +  9); p = p > 1 ? p : 1; r1 = lg[NC * p + lane];
            bstep(r2); p = len - 1 - (k + 10); p = p > 1 ? p : 1; r2 = lg[NC * p + lane];
            bstep(r3); p = len - 1 - (k + 11); p = p > 1 ? p : 1; r3 = lg[NC * p + lane];
            bstep(r4); p = len - 1 - (k + 12); p = p > 1 ? p : 1; r4 = lg[NC * p + lane];
            bstep(r5); p = len - 1 - (k + 13); p = p > 1 ? p : 1; r5 = lg[NC * p + lane];
            bstep(r6); p = len - 1 - (k + 14); p = p > 1 ? p : 1; r6 = lg[NC * p + lane];
            bstep(r7); p = len - 1 - (k + 15); p = p > 1 ? p : 1; r7 = lg[NC * p + lane];
        }
        if (k + 0 < nb) bstep(r0);
        if (k + 1 < nb) bstep(r1);
        if (k + 2 < nb) bstep(r2);
        if (k + 3 < nb) bstep(r3);
        if (k + 4 < nb) bstep(r4);
        if (k + 5 < nb) bstep(r5);
        if (k + 6 < nb) bstep(r6);
        // beta_m = log(vcur) + L
    }

    // ---- publish per-wave results
    xchg[wid][lane] = vcur;
    if (lane == 0) Lsh[wid] = L;

    // ---- gold score: both waves cooperate (128-thread stride), off critical path
    const int* tg = tags + (size_t)n * T;
    float g = 0.f;
    for (int tt = 1 + tid; tt < len; tt += 128) {
        const int cur = tg[tt];
        const int prv = tg[tt - 1];
        g += trans[cur * NC + prv] + lg[tt * NC + cur];
    }
    g = wave_sum_bcast(g);
    if (lane == 0) gsh[wid] = g;

    __syncthreads();

    if (wid == 0) {
        // logZ = L_f + L_b + log( sum_j vf[j] * ub[j] )
        float prod = xchg[0][lane] * xchg[1][lane];
        float ssum = wave_sum_bcast(prod);
        if (lane == 0) {
            float logZ = Lsh[0] + Lsh[1] + __logf(ssum);
            int t0v = tg[0];
            float gold = init_alphas[t0v] + lg[t0v] + gsh[0] + gsh[1];
            out[n] = logZ - gold;
        }
    }
}

extern "C" void kernel_launch(void* const* d_in, const int* in_sizes, int n_in,
                              void* d_out, int out_size, void* d_ws, size_t ws_size,
                              hipStream_t stream)
{
    const float* logits = (const float*)d_in[0];   // [N][T][C] f32
    const float* trans  = (const float*)d_in[1];   // [C][C]    f32
    const float* inita  = (const float*)d_in[2];   // [C]       f32
    const int*   lens   = (const int*)d_in[3];     // [N]       i32
    const int*   tags   = (const int*)d_in[4];     // [N][T]    i32
    float*       out    = (float*)d_out;           // [N]       f32

    const int N = 512, T = 1024;
    crf_nll_kernel<<<N, 128, 0, stream>>>(logits, trans, inita, lens, tags, out, N, T);
}

// Round 12
// 131.819 us; speedup vs baseline: 1.9977x; 1.0350x over previous
//
#include <hip/hip_runtime.h>
#include <cstdint>
#include <cstddef>

#define NC 64
#define LN2 0.6931471805599453f

typedef _Float16 half2_t __attribute__((ext_vector_type(2)));
typedef unsigned int uint32x4 __attribute__((ext_vector_type(4)));

static __device__ __forceinline__ float dot2acc(uint32_t a, uint32_t b, float c) {
#if __has_builtin(__builtin_amdgcn_fdot2)
    return __builtin_amdgcn_fdot2(__builtin_bit_cast(half2_t, a),
                                  __builtin_bit_cast(half2_t, b), c, false);
#else
    half2_t ha = __builtin_bit_cast(half2_t, a), hb = __builtin_bit_cast(half2_t, b);
    return c + (float)ha[0] * (float)hb[0] + (float)ha[1] * (float)hb[1];
#endif
}

template <int CTRL>
static __device__ __forceinline__ float dppf(float x) {
    return __int_as_float(__builtin_amdgcn_update_dpp(
        0, __float_as_int(x), CTRL, 0xf, 0xf, true));
}
static __device__ __forceinline__ float wave_sum_bcast(float x) {
    x = x + dppf<0x111>(x);
    x = x + dppf<0x112>(x);
    x = x + dppf<0x114>(x);
    x = x + dppf<0x118>(x);
    x = x + dppf<0x142>(x);   // row_bcast15
    x = x + dppf<0x143>(x);   // row_bcast31
    return __int_as_float(__builtin_amdgcn_readlane(__float_as_int(x), 63));
}

// DPP ctrls: 0xB1 ^1 (quad), 0x4E ^2 (quad), 0x141 ^7 (half_mirror), 0x140 ^15 (mirror)

__global__ __launch_bounds__(128, 1)
void crf_nll_kernel(const float* __restrict__ logits,
                    const float* __restrict__ trans,
                    const float* __restrict__ init_alphas,
                    const int*  __restrict__ lengths,
                    const int*  __restrict__ tags,
                    float* __restrict__ out,
                    int N, int T)
{
    const int n = blockIdx.x;
    const int tid = threadIdx.x;
    const int wid = tid >> 6;          // wave 0: forward alpha; wave 1: backward beta
    const int lane = tid & 63;
    const float* lg = logits + (size_t)n * T * NC;
    const int len = lengths[n];        // in [2, T]
    const int Tm1 = T - 1;

    __shared__ __align__(16) uint32_t Etab[2][64 * 32]; // per-lane split-dot layout, f16x2
    __shared__ __align__(16) uint16_t st_pk[2][NC + 8]; // per-wave state exchange (f16)
    __shared__ __align__(16) float xchg[2][NC];
    __shared__ float Lsh[2], gsh[2];

    // ---- fill tables: lane i, word (j,k) holds E-row (i^D(j)), classes (8s+2k, 8s+2k+1)
    //      D(j) = (j&3)|((j&4)<<1)  in {0,1,2,3,8,9,10,11};  s(i) = (i&3)|((i>>1)&4)
    //      tab0 = exp(trans[row][c]) (forward); tab1 = exp(trans[c][row]) (backward, E^T)
    #pragma unroll
    for (int idx = tid; idx < 2 * 64 * 32; idx += 128) {
        int tab = idx >> 11, rem = idx & 2047;
        int i = rem >> 5, wrd = rem & 31;
        int j = wrd >> 2, k = wrd & 3;
        int D = (j & 3) | ((j & 4) << 1);
        int row = i ^ D;
        int s = (i & 3) | ((i >> 1) & 4);
        int c0 = 8 * s + 2 * k, c1 = c0 + 1;
        float x0 = tab == 0 ? trans[row * NC + c0] : trans[c0 * NC + row];
        float x1 = tab == 0 ? trans[row * NC + c1] : trans[c1 * NC + row];
        uint32_t lo = (uint32_t)__builtin_bit_cast(uint16_t, (_Float16)__expf(x0));
        uint32_t hi = (uint32_t)__builtin_bit_cast(uint16_t, (_Float16)__expf(x1));
        Etab[tab][i * 32 + wrd] = lo | (hi << 16);
    }
    __syncthreads();

    // ---- hoist this wave's 128B E block into 8 vec4 regs via inline asm
    uint32x4 e0, e1, e2, e3, e4, e5, e6, e7;
    {
        uint32_t e_addr = (uint32_t)(uintptr_t)&Etab[wid][0] + (uint32_t)(lane * 128);
        asm volatile(
            "ds_read_b128 %0, %8 offset:0\n\t"
            "ds_read_b128 %1, %8 offset:16\n\t"
            "ds_read_b128 %2, %8 offset:32\n\t"
            "ds_read_b128 %3, %8 offset:48\n\t"
            "ds_read_b128 %4, %8 offset:64\n\t"
            "ds_read_b128 %5, %8 offset:80\n\t"
            "ds_read_b128 %6, %8 offset:96\n\t"
            "ds_read_b128 %7, %8 offset:112\n\t"
            "s_waitcnt lgkmcnt(0)"
            : "=&v"(e0), "=&v"(e1), "=&v"(e2), "=&v"(e3),
              "=&v"(e4), "=&v"(e5), "=&v"(e6), "=&v"(e7)
            : "v"(e_addr)
            : "memory");
        __builtin_amdgcn_sched_barrier(0);
    }

    const int m  = (len - 1) >> 1;     // forward does m steps
    const int nb = len - 1 - m;        // backward does nb >= 1 steps

    uint16_t* my_pk = st_pk[wid];
    const int s_lane = (lane & 3) | ((lane >> 1) & 4);
    const uint32x4* wchunk = reinterpret_cast<const uint32x4*>(my_pk + 8 * s_lane);

    float L = 0.f, vcur = 1.0f, s_cur = 1.0f, dL = 0.0f;

    // split-dot + DPP-tree: returns full dot for row `lane`
    auto dotE = [&]() -> float {
        const uint32x4 w = wchunk[0];              // ONE ds_read_b128 (8-way broadcast)
        float p0, p1, p2, p3, p4, p5, p6, p7;
        p0 = dot2acc(e0.x, w.x, dot2acc(e0.y, w.y, dot2acc(e0.z, w.z, dot2acc(e0.w, w.w, 0.f))));
        p1 = dot2acc(e1.x, w.x, dot2acc(e1.y, w.y, dot2acc(e1.z, w.z, dot2acc(e1.w, w.w, 0.f))));
        p2 = dot2acc(e2.x, w.x, dot2acc(e2.y, w.y, dot2acc(e2.z, w.z, dot2acc(e2.w, w.w, 0.f))));
        p3 = dot2acc(e3.x, w.x, dot2acc(e3.y, w.y, dot2acc(e3.z, w.z, dot2acc(e3.w, w.w, 0.f))));
        p4 = dot2acc(e4.x, w.x, dot2acc(e4.y, w.y, dot2acc(e4.z, w.z, dot2acc(e4.w, w.w, 0.f))));
        p5 = dot2acc(e5.x, w.x, dot2acc(e5.y, w.y, dot2acc(e5.z, w.z, dot2acc(e5.w, w.w, 0.f))));
        p6 = dot2acc(e6.x, w.x, dot2acc(e6.y, w.y, dot2acc(e6.z, w.z, dot2acc(e6.w, w.w, 0.f))));
        p7 = dot2acc(e7.x, w.x, dot2acc(e7.y, w.y, dot2acc(e7.z, w.z, dot2acc(e7.w, w.w, 0.f))));
        // butterfly reduce over lanes: p_D holds partial of row lane^D, D={0,1,2,3,8,9,10,11}
        float q0  = p0 + dppf<0xB1>(p1);           // ^1: rows lane, partner covers other classes
        float q2  = p2 + dppf<0xB1>(p3);
        float q8  = p4 + dppf<0xB1>(p5);
        float q10 = p6 + dppf<0xB1>(p7);
        float r0 = q0 + dppf<0x4E>(q2);            // ^2
        float r8 = q8 + dppf<0x4E>(q10);
        float t8 = dppf<0x141>(r8);                // ^7
        return r0 + dppf<0x140>(t8);               // ^15 ∘ ^7 = ^8
    };

    if (wid == 0) {
        // ---------------- forward: alpha_0 .. alpha_m ----------------
        float a0 = init_alphas[lane] + lg[lane];
        L = __int_as_float(__builtin_amdgcn_readfirstlane(__float_as_int(a0))) + 8.f * LN2;
        vcur = __expf(a0 - L);
        my_pk[lane] = __builtin_bit_cast(uint16_t, (_Float16)vcur);

        auto fstep = [&](float raw) {
            float fs = __expf(raw) * s_cur;
            L += dL;
            float v = fs * dotE();
            vcur = v;
            my_pk[lane] = __builtin_bit_cast(uint16_t, (_Float16)v);
            unsigned bits = (unsigned)__builtin_amdgcn_readfirstlane((int)__float_as_uint(v));
            int e = (int)((bits >> 23) & 0xFF);
            s_cur = __uint_as_float((unsigned)(246 - e) << 23);   // 2^(119-e)
            dL    = (float)(e - 119) * LN2;
        };

        float r0 = lg[NC * (1 < Tm1 ? 1 : Tm1) + lane];
        float r1 = lg[NC * (2 < Tm1 ? 2 : Tm1) + lane];
        float r2 = lg[NC * (3 < Tm1 ? 3 : Tm1) + lane];
        float r3 = lg[NC * (4 < Tm1 ? 4 : Tm1) + lane];
        float r4 = lg[NC * (5 < Tm1 ? 5 : Tm1) + lane];
        float r5 = lg[NC * (6 < Tm1 ? 6 : Tm1) + lane];
        float r6 = lg[NC * (7 < Tm1 ? 7 : Tm1) + lane];
        float r7 = lg[NC * (8 < Tm1 ? 8 : Tm1) + lane];

        int t = 1;
        for (; t + 8 <= m + 1; t += 8) {
            int p;
            fstep(r0); p = t +  8; p = p < Tm1 ? p : Tm1; r0 = lg[NC * p + lane];
            fstep(r1); p = t +  9; p = p < Tm1 ? p : Tm1; r1 = lg[NC * p + lane];
            fstep(r2); p = t + 10; p = p < Tm1 ? p : Tm1; r2 = lg[NC * p + lane];
            fstep(r3); p = t + 11; p = p < Tm1 ? p : Tm1; r3 = lg[NC * p + lane];
            fstep(r4); p = t + 12; p = p < Tm1 ? p : Tm1; r4 = lg[NC * p + lane];
            fstep(r5); p = t + 13; p = p < Tm1 ? p : Tm1; r5 = lg[NC * p + lane];
            fstep(r6); p = t + 14; p = p < Tm1 ? p : Tm1; r6 = lg[NC * p + lane];
            fstep(r7); p = t + 15; p = p < Tm1 ? p : Tm1; r7 = lg[NC * p + lane];
        }
        if (t + 0 <= m) fstep(r0);
        if (t + 1 <= m) fstep(r1);
        if (t + 2 <= m) fstep(r2);
        if (t + 3 <= m) fstep(r3);
        if (t + 4 <= m) fstep(r4);
        if (t + 5 <= m) fstep(r5);
        if (t + 6 <= m) fstep(r6);
    } else {
        // ---------------- backward: beta_{len-1}=0 down to beta_m ----------------
        auto bstep = [&](float raw) {
            float p = __expf(raw) * s_cur * vcur;   // own-lane product, then E^T gather
            L += dL;
            my_pk[lane] = __builtin_bit_cast(uint16_t, (_Float16)p);
            float u = dotE();
            vcur = u;
            unsigned bits = (unsigned)__builtin_amdgcn_readfirstlane((int)__float_as_uint(u));
            int e = (int)((bits >> 23) & 0xFF);
            s_cur = __uint_as_float((unsigned)(246 - e) << 23);   // 2^(119-e)
            dL    = (float)(e - 119) * LN2;
        };

        int p0i;
        p0i = len - 1; p0i = p0i > 1 ? p0i : 1; float r0 = lg[NC * p0i + lane];
        p0i = len - 2; p0i = p0i > 1 ? p0i : 1; float r1 = lg[NC * p0i + lane];
        p0i = len - 3; p0i = p0i > 1 ? p0i : 1; float r2 = lg[NC * p0i + lane];
        p0i = len - 4; p0i = p0i > 1 ? p0i : 1; float r3 = lg[NC * p0i + lane];
        p0i = len - 5; p0i = p0i > 1 ? p0i : 1; float r4 = lg[NC * p0i + lane];
        p0i = len - 6; p0i = p0i > 1 ? p0i : 1; float r5 = lg[NC * p0i + lane];
        p0i = len - 7; p0i = p0i > 1 ? p0i : 1; float r6 = lg[NC * p0i + lane];
        p0i = len - 8; p0i = p0i > 1 ? p0i : 1; float r7 = lg[NC * p0i + lane];

        int k = 0;
        for (; k + 8 <= nb; k += 8) {
            int p;
            bstep(r0); p = len - 1 - (k +  8); p = p > 1 ? p : 1; r0 = lg[NC * p + lane];
            bstep(r1); p = len - 1 - (k +  9); p = p > 1 ? p : 1; r1 = lg[NC * p + lane];
            bstep(r2); p = len - 1 - (k + 10); p = p > 1 ? p : 1; r2 = lg[NC * p + lane];
            bstep(r3); p = len - 1 - (k + 11); p = p > 1 ? p : 1; r3 = lg[NC * p + lane];
            bstep(r4); p = len - 1 - (k + 12); p = p > 1 ? p : 1; r4 = lg[NC * p + lane];
            bstep(r5); p = len - 1 - (k + 13); p = p > 1 ? p : 1; r5 = lg[NC * p + lane];
            bstep(r6); p = len - 1 - (k + 14); p = p > 1 ? p : 1; r6 = lg[NC * p + lane];
            bstep(r7); p = len - 1 - (k + 15); p = p > 1 ? p : 1; r7 = lg[NC * p + lane];
        }
        if (k + 0 < nb) bstep(r0);
        if (k + 1 < nb) bstep(r1);
        if (k + 2 < nb) bstep(r2);
        if (k + 3 < nb) bstep(r3);
        if (k + 4 < nb) bstep(r4);
        if (k + 5 < nb) bstep(r5);
        if (k + 6 < nb) bstep(r6);
    }

    // ---- publish per-wave results
    xchg[wid][lane] = vcur;
    if (lane == 0) Lsh[wid] = L;

    // ---- gold score: both waves cooperate (128-thread stride)
    const int* tg = tags + (size_t)n * T;
    float g = 0.f;
    for (int tt = 1 + tid; tt < len; tt += 128) {
        const int cur = tg[tt];
        const int prv = tg[tt - 1];
        g += trans[cur * NC + prv] + lg[tt * NC + cur];
    }
    g = wave_sum_bcast(g);
    if (lane == 0) gsh[wid] = g;

    __syncthreads();

    if (wid == 0) {
        float prod = xchg[0][lane] * xchg[1][lane];
        float ssum = wave_sum_bcast(prod);
        if (lane == 0) {
            float logZ = Lsh[0] + Lsh[1] + __logf(ssum);
            int t0v = tg[0];
            float gold = init_alphas[t0v] + lg[t0v] + gsh[0] + gsh[1];
            out[n] = logZ - gold;
        }
    }
}

extern "C" void kernel_launch(void* const* d_in, const int* in_sizes, int n_in,
                              void* d_out, int out_size, void* d_ws, size_t ws_size,
                              hipStream_t stream)
{
    const float* logits = (const float*)d_in[0];   // [N][T][C] f32
    const float* trans  = (const float*)d_in[1];   // [C][C]    f32
    const float* inita  = (const float*)d_in[2];   // [C]       f32
    const int*   lens   = (const int*)d_in[3];     // [N]       i32
    const int*   tags   = (const int*)d_in[4];     // [N][T]    i32
    float*       out    = (float*)d_out;           // [N]       f32

    const int N = 512, T = 1024;
    crf_nll_kernel<<<N, 128, 0, stream>>>(logits, trans, inita, lens, tags, out, N, T);
}